// Round 7
// baseline (764.292 us; speedup 1.0000x reference)
//
#include <hip/hip_runtime.h>
#include <hip/hip_bf16.h>

// Problem constants (ChainGraphDQN)
#define NN 200000      // nodes
#define FIN 128        // in features
#define NE 3200000     // edges
#define NG 4096        // graphs
#define HC 16          // GCN out channels
#define D1 64          // MLP hidden
#define NM 12          // heads
#define NA 8           // actions

// edge_index: planar [2,E] C-order (src block then dst block) — numpy default.
// Scratch in module __device__ globals.
__device__ float g_h[NN * HC];        // 12.8 MB
__device__ float g_agg[NN * HC];      // 12.8 MB
__device__ float g_dinv[NN];
__device__ int   g_degi[NN];
__device__ float g_pooled[NG * HC];
__device__ float g_cnt[NG];

__device__ __forceinline__ void atomAddF(float* p, float v) {
    unsafeAtomicAdd(p, v);
}

// ---------------- Kernel Z: zero the accumulators ---------------------------
__global__ __launch_bounds__(256) void k_zero() {
    int i = blockIdx.x * 256 + threadIdx.x;
    if (i < NN * HC) g_agg[i] = 0.f;
    if (i < NN) g_degi[i] = 0;
    if (i < NG * HC) g_pooled[i] = 0.f;
    if (i < NG) g_cnt[i] = 0.f;
}

// ---------------- Kernel A: h = x @ conv_w ----------------------------------
__global__ __launch_bounds__(256) void k_xw(const float* __restrict__ x,
                                            const float* __restrict__ conv_w) {
    __shared__ float s_w[FIN * HC];
    for (int i = threadIdx.x; i < FIN * HC; i += 256) s_w[i] = conv_w[i];
    __syncthreads();
    int row = blockIdx.x * 256 + threadIdx.x;
    if (row >= NN) return;
    const float4* xr = (const float4*)(x + (size_t)row * FIN);
    float acc[HC];
#pragma unroll
    for (int c = 0; c < HC; c++) acc[c] = 0.f;
    for (int kk = 0; kk < FIN / 4; kk++) {
        float4 p = xr[kk];
        float xf[4] = {p.x, p.y, p.z, p.w};
#pragma unroll
        for (int j = 0; j < 4; j++) {
            const float* wr = &s_w[(kk * 4 + j) * HC];
#pragma unroll
            for (int c = 0; c < HC; c++) acc[c] = fmaf(xf[j], wr[c], acc[c]);
        }
    }
    float4* hr = (float4*)(g_h + (size_t)row * HC);
#pragma unroll
    for (int q = 0; q < 4; q++)
        hr[q] = make_float4(acc[4 * q], acc[4 * q + 1], acc[4 * q + 2], acc[4 * q + 3]);
}

// ---------------- Kernel B: degree count over dst ---------------------------
__global__ void k_deg(const int* __restrict__ ei) {
    int e = blockIdx.x * blockDim.x + threadIdx.x;
    if (e >= NE) return;
    atomicAdd(&g_degi[ei[NE + e]], 1);
}

// ---------------- Kernel B2: dinv = rsqrt(deg+1)  (+1 = self-loop) ----------
__global__ void k_dinv() {
    int i = blockIdx.x * blockDim.x + threadIdx.x;
    if (i < NN) g_dinv[i] = rsqrtf((float)(g_degi[i] + 1));
}

// ---------------- Kernel C: edge scatter: agg[d] += h[s]*dinv[s] ------------
__global__ __launch_bounds__(256) void k_scatter(const int* __restrict__ ei) {
    long long t = (long long)blockIdx.x * 256 + threadIdx.x;
    if (t >= (long long)NE * HC) return;
    int e = (int)(t >> 4), c = (int)(t & 15);
    int s = ei[e];
    int d = ei[NE + e];
    float v = g_h[(size_t)s * HC + c] * g_dinv[s];
    atomAddF(&g_agg[(size_t)d * HC + c], v);
}

// ---------------- Kernel D: finish conv (relu) + mean-pool scatter ----------
__global__ __launch_bounds__(256) void k_pool(const float* __restrict__ conv_b,
                                              const int* __restrict__ batch) {
    long long t = (long long)blockIdx.x * 256 + threadIdx.x;
    if (t >= (long long)NN * HC) return;
    int i = (int)(t >> 4), c = (int)(t & 15);
    float di = g_dinv[i];
    float val = di * (g_agg[t] + g_h[t] * di) + conv_b[c];
    float r = val > 0.f ? val : 0.f;
    int b = batch[i];
    atomAddF(&g_pooled[(size_t)b * HC + c], r);
    if (c == 0) atomAddF(&g_cnt[b], 1.0f);
}

// ---------------- Kernel E: MLP + heads (f32 OUTPUT — hypothesis under test)
__global__ __launch_bounds__(256) void k_mlp(const float* __restrict__ w1,
                                             const float* __restrict__ b1,
                                             const float* __restrict__ w2,
                                             const float* __restrict__ b2,
                                             const float* __restrict__ head_w,
                                             const float* __restrict__ head_b,
                                             float* __restrict__ out) {
    __shared__ float s_w1[HC * D1];
    __shared__ float s_b1[D1];
    __shared__ float s_w2[D1 * D1];
    __shared__ float s_b2[D1];
    __shared__ float s_hw[NM * D1 * NA];
    __shared__ float s_hb[NM * NA];
    __shared__ float s_p[4][HC];
    __shared__ float s_g1[4][D1];
    __shared__ float s_g2[4][D1];

    int tid = threadIdx.x;
    for (int i = tid; i < HC * D1; i += 256) s_w1[i] = w1[i];
    for (int i = tid; i < D1; i += 256) { s_b1[i] = b1[i]; s_b2[i] = b2[i]; }
    for (int i = tid; i < D1 * D1; i += 256) s_w2[i] = w2[i];
    for (int i = tid; i < NM * D1 * NA; i += 256) s_hw[i] = head_w[i];
    for (int i = tid; i < NM * NA; i += 256) s_hb[i] = head_b[i];

    int grp = tid >> 6, lane = tid & 63;
    int g = blockIdx.x * 4 + grp;
    if (lane < HC) {
        float cc = g_cnt[g];
        s_p[grp][lane] = g_pooled[g * HC + lane] / fmaxf(cc, 1.0f);
    }
    __syncthreads();

    // layer 1: [16] -> [64], elu
    {
        float a = s_b1[lane];
#pragma unroll
        for (int c = 0; c < HC; c++) a = fmaf(s_p[grp][c], s_w1[c * D1 + lane], a);
        s_g1[grp][lane] = a > 0.f ? a : expm1f(a);
    }
    __syncthreads();
    // layer 2: [64] -> [64], elu
    {
        float a = s_b2[lane];
#pragma unroll
        for (int d = 0; d < D1; d++) a = fmaf(s_g1[grp][d], s_w2[d * D1 + lane], a);
        s_g2[grp][lane] = a > 0.f ? a : expm1f(a);
    }
    __syncthreads();
    // heads: [64] -> [12*8]
    for (int idx = lane; idx < NM * NA; idx += 64) {
        int m = idx >> 3, a = idx & 7;
        float v = s_hb[idx];
#pragma unroll
        for (int d = 0; d < D1; d++)
            v = fmaf(s_g2[grp][d], s_hw[m * (D1 * NA) + d * NA + a], v);
        out[(size_t)g * (NM * NA) + idx] = v;   // f32 store
    }
}

extern "C" void kernel_launch(void* const* d_in, const int* in_sizes, int n_in,
                              void* d_out, int out_size, void* d_ws, size_t ws_size,
                              hipStream_t stream) {
    const float* x      = (const float*)d_in[0];
    const int*   ei     = (const int*)d_in[1];
    const int*   batch  = (const int*)d_in[2];
    const float* conv_w = (const float*)d_in[3];
    const float* conv_b = (const float*)d_in[4];
    const float* w1     = (const float*)d_in[5];
    const float* b1     = (const float*)d_in[6];
    const float* w2     = (const float*)d_in[7];
    const float* b2     = (const float*)d_in[8];
    const float* head_w = (const float*)d_in[9];
    const float* head_b = (const float*)d_in[10];
    float* out = (float*)d_out;

    k_zero<<<(NN * HC + 255) / 256, 256, 0, stream>>>();
    k_xw<<<(NN + 255) / 256, 256, 0, stream>>>(x, conv_w);
    k_deg<<<(NE + 255) / 256, 256, 0, stream>>>(ei);
    k_dinv<<<(NN + 255) / 256, 256, 0, stream>>>();
    k_scatter<<<(int)(((long long)NE * HC + 255) / 256), 256, 0, stream>>>(ei);
    k_pool<<<(int)(((long long)NN * HC + 255) / 256), 256, 0, stream>>>(conv_b, batch);
    k_mlp<<<NG / 4, 256, 0, stream>>>(w1, b1, w2, b2, head_w, head_b, out);
}

// Round 8
// 608.958 us; speedup vs baseline: 1.2551x; 1.2551x over previous
//
#include <hip/hip_runtime.h>
#include <hip/hip_bf16.h>

// Problem constants (ChainGraphDQN)
#define NN 200000      // nodes
#define FIN 128        // in features
#define NE 3200000     // edges
#define NG 4096        // graphs
#define HC 16          // GCN out channels
#define D1 64          // MLP hidden
#define NM 12          // heads
#define NA 8           // actions
#define NBLK 782       // ceil(NN/256)

// Scratch in module __device__ globals.
__device__ float g_h[NN * HC];        // 12.8 MB
__device__ int2  g_csr[NE];           // 25.6 MB (src, bitcast dinv[src])
__device__ int   g_degi[NN];
__device__ int   g_offs[NN];
__device__ int   g_cursor[NN];
__device__ float g_dinv[NN];
__device__ int   g_bsum[1024];
__device__ int   g_bpre[1024];
__device__ float g_pooled[NG * HC];
__device__ float g_cnt[NG];

__device__ __forceinline__ void atomAddF(float* p, float v) {
    unsafeAtomicAdd(p, v);
}

// ---------------- zero the accumulators -------------------------------------
__global__ __launch_bounds__(256) void k_zero() {
    int i = blockIdx.x * 256 + threadIdx.x;
    if (i < NN) g_degi[i] = 0;
    if (i < NG * HC) g_pooled[i] = 0.f;
    if (i < NG) g_cnt[i] = 0.f;
}

// ---------------- h = x @ conv_w (LDS-tiled, coalesced) ---------------------
// 64 rows/block; x-tile staged in LDS (stride 132 kills 16-way bank conflict).
__global__ __launch_bounds__(256) void k_xw(const float* __restrict__ x,
                                            const float* __restrict__ conv_w) {
    __shared__ float s_w[FIN * HC];      // 8 KB
    __shared__ float s_x[64 * 132];      // 33.8 KB
    int t = threadIdx.x;
    for (int i = t; i < FIN * HC; i += 256) s_w[i] = conv_w[i];
    int base = blockIdx.x * 64;
    for (int idx = t; idx < 64 * FIN; idx += 256) {
        int r = idx >> 7, k = idx & 127;
        s_x[r * 132 + k] = x[(size_t)(base + r) * FIN + k];
    }
    __syncthreads();
    int c = t & 15, rg = t >> 4;         // rg in 0..15; rows rg+16q
    float acc[4] = {0.f, 0.f, 0.f, 0.f};
    for (int k = 0; k < FIN; k++) {
        float w = s_w[k * HC + c];
#pragma unroll
        for (int q = 0; q < 4; q++)
            acc[q] = fmaf(s_x[(rg + 16 * q) * 132 + k], w, acc[q]);
    }
#pragma unroll
    for (int q = 0; q < 4; q++)
        g_h[(size_t)(base + rg + 16 * q) * HC + c] = acc[q];
}

// ---------------- degree count over dst -------------------------------------
__global__ void k_deg(const int* __restrict__ ei) {
    int e = blockIdx.x * blockDim.x + threadIdx.x;
    if (e >= NE) return;
    atomicAdd(&g_degi[ei[NE + e]], 1);
}

// ---------------- scan step A: per-block degree sums ------------------------
__global__ __launch_bounds__(256) void k_sumA() {
    __shared__ int s[256];
    int t = threadIdx.x;
    int i = blockIdx.x * 256 + t;
    s[t] = (i < NN) ? g_degi[i] : 0;
    __syncthreads();
    for (int o = 128; o > 0; o >>= 1) {
        if (t < o) s[t] += s[t + o];
        __syncthreads();
    }
    if (t == 0) g_bsum[blockIdx.x] = s[0];
}

// ---------------- scan step B: exclusive scan of block sums -----------------
__global__ __launch_bounds__(1024) void k_scanB() {
    __shared__ int s[1024];
    int t = threadIdx.x;
    int v = (t < NBLK) ? g_bsum[t] : 0;
    s[t] = v;
    __syncthreads();
    for (int o = 1; o < 1024; o <<= 1) {
        int u = (t >= o) ? s[t - o] : 0;
        __syncthreads();
        s[t] += u;
        __syncthreads();
    }
    if (t < NBLK) g_bpre[t] = s[t] - v;   // exclusive
}

// ---------------- scan step C: offsets, cursors, dinv -----------------------
__global__ __launch_bounds__(256) void k_scanC() {
    __shared__ int s[256];
    int t = threadIdx.x;
    int i = blockIdx.x * 256 + t;
    int d = (i < NN) ? g_degi[i] : 0;
    s[t] = d;
    __syncthreads();
    for (int o = 1; o < 256; o <<= 1) {
        int u = (t >= o) ? s[t - o] : 0;
        __syncthreads();
        s[t] += u;
        __syncthreads();
    }
    if (i < NN) {
        int off = g_bpre[blockIdx.x] + s[t] - d;   // exclusive within block
        g_offs[i] = off;
        g_cursor[i] = off;
        g_dinv[i] = rsqrtf((float)(d + 1));        // +1 = self-loop
    }
}

// ---------------- CSR build: slot edges by dst ------------------------------
__global__ void k_place(const int* __restrict__ ei) {
    int e = blockIdx.x * blockDim.x + threadIdx.x;
    if (e >= NE) return;
    int s = ei[e], d = ei[NE + e];
    int pos = atomicAdd(&g_cursor[d], 1);
    g_csr[pos] = make_int2(s, __float_as_int(g_dinv[s]));
}

// ---------------- gather + relu + fused mean-pool (LDS pre-agg) -------------
// 16 nodes/block x 16 channels. Sorted batch => slot = b-b0 in [0,16) (safe
// fallback to direct atomic otherwise).
__global__ __launch_bounds__(256) void k_gather(const float* __restrict__ conv_b,
                                                const int* __restrict__ batch) {
    __shared__ float s_pool[16 * 16];
    __shared__ int s_cnt[16];
    __shared__ int s_b0;
    int t = threadIdx.x;
    int node = blockIdx.x * 16 + (t >> 4);
    int c = t & 15;
    s_pool[t] = 0.f;
    if (t < 16) s_cnt[t] = 0;
    if (t == 0) s_b0 = batch[blockIdx.x * 16];
    __syncthreads();

    int off = g_offs[node], dg = g_degi[node];
    float di = g_dinv[node];
    float acc = 0.f;
    for (int j = 0; j < dg; j++) {
        int2 p = g_csr[off + j];
        acc = fmaf(g_h[(size_t)p.x * HC + c], __int_as_float(p.y), acc);
    }
    float val = di * (acc + g_h[(size_t)node * HC + c] * di) + conv_b[c];
    float r = val > 0.f ? val : 0.f;

    int b = batch[node];
    int slot = b - s_b0;
    if (slot < 16) {
        atomicAdd(&s_pool[slot * 16 + c], r);
        if (c == 0) atomicAdd(&s_cnt[slot], 1);
    } else {                      // astronomically rare (16 empty graphs in a row)
        atomAddF(&g_pooled[(size_t)b * HC + c], r);
        if (c == 0) atomAddF(&g_cnt[b], 1.f);
    }
    __syncthreads();
    int slot2 = t >> 4;
    if (s_cnt[slot2] > 0)
        atomAddF(&g_pooled[(size_t)(s_b0 + slot2) * HC + c], s_pool[t]);
    if (t < 16 && s_cnt[t] > 0)
        atomAddF(&g_cnt[s_b0 + t], (float)s_cnt[t]);
}

// ---------------- MLP + heads (f32 output) ----------------------------------
__global__ __launch_bounds__(256) void k_mlp(const float* __restrict__ w1,
                                             const float* __restrict__ b1,
                                             const float* __restrict__ w2,
                                             const float* __restrict__ b2,
                                             const float* __restrict__ head_w,
                                             const float* __restrict__ head_b,
                                             float* __restrict__ out) {
    __shared__ float s_w1[HC * D1];
    __shared__ float s_b1[D1];
    __shared__ float s_w2[D1 * D1];
    __shared__ float s_b2[D1];
    __shared__ float s_hw[NM * D1 * NA];
    __shared__ float s_hb[NM * NA];
    __shared__ float s_p[4][HC];
    __shared__ float s_g1[4][D1];
    __shared__ float s_g2[4][D1];

    int tid = threadIdx.x;
    for (int i = tid; i < HC * D1; i += 256) s_w1[i] = w1[i];
    for (int i = tid; i < D1; i += 256) { s_b1[i] = b1[i]; s_b2[i] = b2[i]; }
    for (int i = tid; i < D1 * D1; i += 256) s_w2[i] = w2[i];
    for (int i = tid; i < NM * D1 * NA; i += 256) s_hw[i] = head_w[i];
    for (int i = tid; i < NM * NA; i += 256) s_hb[i] = head_b[i];

    int grp = tid >> 6, lane = tid & 63;
    int g = blockIdx.x * 4 + grp;
    if (lane < HC) {
        float cc = g_cnt[g];
        s_p[grp][lane] = g_pooled[g * HC + lane] / fmaxf(cc, 1.0f);
    }
    __syncthreads();
    {
        float a = s_b1[lane];
#pragma unroll
        for (int c = 0; c < HC; c++) a = fmaf(s_p[grp][c], s_w1[c * D1 + lane], a);
        s_g1[grp][lane] = a > 0.f ? a : expm1f(a);
    }
    __syncthreads();
    {
        float a = s_b2[lane];
#pragma unroll
        for (int d = 0; d < D1; d++) a = fmaf(s_g1[grp][d], s_w2[d * D1 + lane], a);
        s_g2[grp][lane] = a > 0.f ? a : expm1f(a);
    }
    __syncthreads();
    for (int idx = lane; idx < NM * NA; idx += 64) {
        int m = idx >> 3, a = idx & 7;
        float v = s_hb[idx];
#pragma unroll
        for (int d = 0; d < D1; d++)
            v = fmaf(s_g2[grp][d], s_hw[m * (D1 * NA) + d * NA + a], v);
        out[(size_t)g * (NM * NA) + idx] = v;
    }
}

extern "C" void kernel_launch(void* const* d_in, const int* in_sizes, int n_in,
                              void* d_out, int out_size, void* d_ws, size_t ws_size,
                              hipStream_t stream) {
    const float* x      = (const float*)d_in[0];
    const int*   ei     = (const int*)d_in[1];
    const int*   batch  = (const int*)d_in[2];
    const float* conv_w = (const float*)d_in[3];
    const float* conv_b = (const float*)d_in[4];
    const float* w1     = (const float*)d_in[5];
    const float* b1     = (const float*)d_in[6];
    const float* w2     = (const float*)d_in[7];
    const float* b2     = (const float*)d_in[8];
    const float* head_w = (const float*)d_in[9];
    const float* head_b = (const float*)d_in[10];
    float* out = (float*)d_out;

    k_zero<<<NBLK, 256, 0, stream>>>();
    k_xw<<<NN / 64, 256, 0, stream>>>(x, conv_w);
    k_deg<<<(NE + 255) / 256, 256, 0, stream>>>(ei);
    k_sumA<<<NBLK, 256, 0, stream>>>();
    k_scanB<<<1, 1024, 0, stream>>>();
    k_scanC<<<NBLK, 256, 0, stream>>>();
    k_place<<<(NE + 255) / 256, 256, 0, stream>>>(ei);
    k_gather<<<NN / 16, 256, 0, stream>>>(conv_b, batch);
    k_mlp<<<NG / 4, 256, 0, stream>>>(w1, b1, w2, b2, head_w, head_b, out);
}